// Round 13
// baseline (960.135 us; speedup 1.0000x reference)
//
#include <hip/hip_runtime.h>
#include <hip/hip_cooperative_groups.h>
#include <math.h>

namespace cg = cooperative_groups;

#define NN 100000
#define NE 3200000
#define NBKT 782        // ceil(NN/128) buckets of 128 nodes
#define NBLK 196        // histogram/scatter blocks
#define EPB 16384       // edges per block (196*16384 >= NE)
#define BCAP 6144       // per-bucket capacity
#define HTPB 1024       // fat blocks for hist/scatter
#define NMB 512         // mega blocks (2 per CU)
#define MTPB 512        // mega threads per block
#define SLICE_CAP 8064  // LDS edge slice capacity (64512 B); max actual ~6350

static constexpr int TPB = 256;
static constexpr int GRID_N = (NN + TPB - 1) / TPB;       // 391

// ---------------- init small state ----------------
__global__ void k_init(const int* __restrict__ kptr, unsigned* __restrict__ prefix,
                       int* __restrict__ target, double* __restrict__ stats) {
  *prefix = 0u;
  *target = *kptr;
  stats[0] = 0.0;
  stats[1] = 0.0;
}

// ---------------- K1: per-block LDS histogram over 782 buckets ----------------
__global__ void b_hist(const int* __restrict__ dst, int* __restrict__ histT) {
  __shared__ int h[NBKT];
  for (int i = threadIdx.x; i < NBKT; i += HTPB) h[i] = 0;
  __syncthreads();
  int base = blockIdx.x * EPB;
  #pragma unroll 4
  for (int i = 0; i < EPB / HTPB; ++i) {
    int e = base + i * HTPB + threadIdx.x;
    if (e < NE) atomicAdd(&h[dst[e] >> 7], 1);
  }
  __syncthreads();
  for (int i = threadIdx.x; i < NBKT; i += HTPB)
    histT[i * NBLK + blockIdx.x] = h[i];
}

// ---------------- K2a: exclusive scan of each bucket row, in place ----------------
__global__ void b_rowscan(int* __restrict__ histT, int* __restrict__ rowsum) {
  int r = blockIdx.x, lane = threadIdx.x;   // 64 lanes
  int base = r * NBLK;
  int v[4]; int s = 0;
  #pragma unroll
  for (int i = 0; i < 4; ++i) {
    int c = lane * 4 + i;
    v[i] = (c < NBLK) ? histT[base + c] : 0;
    s += v[i];
  }
  int pre = s;
  for (int off = 1; off < 64; off <<= 1) {
    int t = __shfl_up(pre, off);
    if (lane >= off) pre += t;
  }
  int excl = pre - s;
  #pragma unroll
  for (int i = 0; i < 4; ++i) {
    int c = lane * 4 + i;
    if (c < NBLK) histT[base + c] = excl;
    excl += v[i];
  }
  if (lane == 63) rowsum[r] = pre;
}

// ---------------- K2b: bucket bases ----------------
__global__ void b_base(const int* __restrict__ rowsum, int* __restrict__ bucketBase,
                       int* __restrict__ rowptr) {
  if (threadIdx.x == 0) {
    int acc = 0;
    for (int b = 0; b < NBKT; ++b) { bucketBase[b] = acc; acc += rowsum[b]; }
    bucketBase[NBKT] = NE;
    rowptr[NN] = NE;
  }
}

// ---------------- K3: scatter edges grouped by bucket (LDS cursors) ----------------
__global__ void b_scatter(const int* __restrict__ src, const int* __restrict__ dst,
                          const float* __restrict__ ea, const int* __restrict__ histT,
                          const int* __restrict__ bucketBase, int2* __restrict__ grouped) {
  __shared__ int cursor[NBKT];
  for (int b = threadIdx.x; b < NBKT; b += HTPB)
    cursor[b] = bucketBase[b] + histT[b * NBLK + blockIdx.x];
  __syncthreads();
  int base = blockIdx.x * EPB;
  #pragma unroll 4
  for (int i = 0; i < EPB / HTPB; ++i) {
    int e = base + i * HTPB + threadIdx.x;
    if (e < NE) {
      int d = dst[e];
      int pos = atomicAdd(&cursor[d >> 7], 1);
      int meta = ((d & 127) << 17) | src[e];
      grouped[pos] = make_int2(meta, __float_as_int(fabsf(ea[e])));
    }
  }
}

// ---------------- K4: per-bucket LDS counting sort + rowptr + packed (x, dinv) ----------------
__global__ void __launch_bounds__(512) b_sortdeg(const int* __restrict__ bucketBase,
                                                 const int2* __restrict__ grouped,
                                                 const float* __restrict__ x,
                                                 int2* __restrict__ ed, int* __restrict__ rowptr,
                                                 float2* __restrict__ xd) {
  __shared__ int hist[128];
  __shared__ float degf[128];
  __shared__ int binoff[128];
  __shared__ int cursor[128];
  __shared__ int2 out[BCAP];
  int b = blockIdx.x, t = threadIdx.x;
  int base = bucketBase[b], n = bucketBase[b + 1] - base;
  if (t < 128) { hist[t] = 0; degf[t] = 0.0f; }
  __syncthreads();
  for (int j = t; j < n; j += 512) {
    int2 el = grouped[base + j];
    int dl = el.x >> 17;
    atomicAdd(&hist[dl], 1);
    atomicAdd(&degf[dl], __int_as_float(el.y));
  }
  __syncthreads();
  if (t == 0) {
    int acc = 0;
    for (int i = 0; i < 128; ++i) { binoff[i] = acc; acc += hist[i]; }
  }
  __syncthreads();
  if (t < 128) {
    cursor[t] = binoff[t];
    int node = b * 128 + t;
    if (node < NN) {
      rowptr[node] = base + binoff[t];
      float dg = degf[t];
      float dv = (dg > 0.0f) ? (1.0f / sqrtf(dg)) : 0.0f;
      xd[node] = make_float2(x[node], dv);
    }
  }
  __syncthreads();
  for (int j = t; j < n; j += 512) {
    int2 el = grouped[base + j];
    int dl = el.x >> 17;
    int pos = atomicAdd(&cursor[dl], 1);
    if (pos < BCAP) out[pos] = el;
  }
  __syncthreads();
  for (int j = t; j < n; j += 512) {
    int2 el = out[j];
    ed[base + j] = make_int2(el.x & 0x1FFFF, el.y);
  }
}

// ---------------- edge-balanced node ranges for mega blocks ----------------
__global__ void e_ranges(const int* __restrict__ rowptr, int* __restrict__ nb) {
  int b = threadIdx.x + blockIdx.x * 1024;
  if (b > NMB) return;
  if (b == 0) { nb[0] = 0; return; }
  if (b == NMB) { nb[NMB] = NN; return; }
  int targ = (int)(((long long)NE * b) / NMB);
  int lo = 0, hi = NN;
  while (lo < hi) {
    int mid = (lo + hi) >> 1;
    if (rowptr[mid] < targ) lo = mid + 1; else hi = mid;
  }
  nb[b] = lo;
}

// ---------------- persistent cooperative mega-kernel: all 9 propagations ----------------
#define SPROP(GSRC, STORE)                                          \
  for (int m = nlo + g; m < nhi; m += 128) {                        \
    int s0 = rowptr[m], s1e = rowptr[m + 1];                        \
    float acc = 0.f;                                                \
    for (int i = s0 + r; i < s1e; i += 4) {                         \
      int2 e = slice[i - ebase];                                    \
      acc += __int_as_float(e.y) * GSRC[e.x];                       \
    }                                                               \
    acc += __shfl_xor(acc, 1);                                      \
    acc += __shfl_xor(acc, 2);                                      \
    if (r == 0) { STORE; }                                          \
  }

#define PROP8_HEAD(HSRC)                                            \
  for (int m = nlo + g; m < nhi; m += 128) {                        \
    int s0 = rowptr[m], s1e = rowptr[m + 1];                        \
    float a0=0,a1=0,a2=0,a3=0,a4=0,a5=0,a6=0,a7=0;                  \
    for (int i = s0 + r; i < s1e; i += 4) {                         \
      int2 e = slice[i - ebase];                                    \
      float w = __int_as_float(e.y);                                \
      const float4* hp = (const float4*)(HSRC + (size_t)e.x * 8);   \
      float4 xx = hp[0], yy = hp[1];                                \
      a0 += w*xx.x; a1 += w*xx.y; a2 += w*xx.z; a3 += w*xx.w;       \
      a4 += w*yy.x; a5 += w*yy.y; a6 += w*yy.z; a7 += w*yy.w;       \
    }                                                               \
    a0+=__shfl_xor(a0,1); a1+=__shfl_xor(a1,1); a2+=__shfl_xor(a2,1); a3+=__shfl_xor(a3,1); \
    a4+=__shfl_xor(a4,1); a5+=__shfl_xor(a5,1); a6+=__shfl_xor(a6,1); a7+=__shfl_xor(a7,1); \
    a0+=__shfl_xor(a0,2); a1+=__shfl_xor(a1,2); a2+=__shfl_xor(a2,2); a3+=__shfl_xor(a3,2); \
    a4+=__shfl_xor(a4,2); a5+=__shfl_xor(a5,2); a6+=__shfl_xor(a6,2); a7+=__shfl_xor(a7,2);

__global__ void __launch_bounds__(MTPB) mega(
    const int* __restrict__ rowptr, const int2* __restrict__ edg,
    const float2* __restrict__ xd, const int* __restrict__ nb,
    const float* __restrict__ W1, const float* __restrict__ b1,
    const float* __restrict__ W2, const float* __restrict__ b2,
    const float* __restrict__ W3, const float* __restrict__ b3,
    float* __restrict__ pA, float* __restrict__ pB,
    float* __restrict__ uu, float* __restrict__ vv,
    float* __restrict__ pA8, float* __restrict__ pB8, float* __restrict__ h1,
    float* __restrict__ g0, float* __restrict__ s1o, float* __restrict__ s2o,
    float* __restrict__ s3o, float* __restrict__ h3, double* __restrict__ stats) {
  __shared__ int2 slice[SLICE_CAP];
  __shared__ double ls[8], ls2[8];
  cg::grid_group grid = cg::this_grid();
  const int tid = threadIdx.x;
  const int r = tid & 3, g = tid >> 2;   // 128 node-slots per block iteration
  const int nlo = nb[blockIdx.x], nhi = nb[blockIdx.x + 1];
  const int ebase = rowptr[nlo];

  // ---- Load slice (finalize weights w = |ea|*dinv[src]*dinv[dst]) fused with P1: pA = S x ----
  for (int m = nlo + g; m < nhi; m += 128) {
    float2 xm = xd[m];
    int s0 = rowptr[m], s1e = rowptr[m + 1];
    float acc = 0.f;
    for (int i = s0 + r; i < s1e; i += 4) {
      int2 e = edg[i];
      float2 v = xd[e.x];
      float w = __int_as_float(e.y) * v.y * xm.y;
      slice[i - ebase] = make_int2(e.x, __float_as_int(w));
      acc += w * v.x;
    }
    acc += __shfl_xor(acc, 1);
    acc += __shfl_xor(acc, 2);
    if (r == 0) pA[m] = acc;
  }
  __syncthreads();
  grid.sync();

  // ---- P2: pB = S pA ----
  SPROP(pA, pB[m] = acc)
  grid.sync();

  // ---- P3: h1 = relu(combine1(x, pA, pB, S pB)) ----
  for (int m = nlo + g; m < nhi; m += 128) {
    int s0 = rowptr[m], s1e = rowptr[m + 1];
    float acc = 0.f;
    for (int i = s0 + r; i < s1e; i += 4) {
      int2 e = slice[i - ebase];
      acc += __int_as_float(e.y) * pB[e.x];
    }
    acc += __shfl_xor(acc, 1);
    acc += __shfl_xor(acc, 2);
    if (r == 0) {
      float h0 = xd[m].x, p1v = pA[m], p2v = pB[m], p3v = acc;
      float* op = h1 + (size_t)m * 8;
      #pragma unroll
      for (int j = 0; j < 8; ++j)
        op[j] = fmaxf(b1[j] + h0 * W1[j] + p1v * W1[8 + j] + p2v * W1[16 + j] + p3v * W1[24 + j], 0.f);
    }
  }
  grid.sync();

  // ---- P4: pA8 = S h1 ----
  PROP8_HEAD(h1)
    if (r == 0) {
      float* op = pA8 + (size_t)m * 8;
      *(float4*)op = make_float4(a0, a1, a2, a3);
      *(float4*)(op + 4) = make_float4(a4, a5, a6, a7);
    }
  }
  grid.sync();

  // ---- P5: pB8 = S pA8 ----
  PROP8_HEAD(pA8)
    if (r == 0) {
      float* op = pB8 + (size_t)m * 8;
      *(float4*)op = make_float4(a0, a1, a2, a3);
      *(float4*)(op + 4) = make_float4(a4, a5, a6, a7);
    }
  }
  grid.sync();

  // ---- P6: c8 = S pB8 (regs); combine8 + layer-3 projections ----
  PROP8_HEAD(pB8)
    if (r == 0) {
      float h[4][8];
      const float4* hp = (const float4*)(h1 + (size_t)m * 8);
      float4 u = hp[0], v4 = hp[1];
      h[0][0]=u.x; h[0][1]=u.y; h[0][2]=u.z; h[0][3]=u.w; h[0][4]=v4.x; h[0][5]=v4.y; h[0][6]=v4.z; h[0][7]=v4.w;
      hp = (const float4*)(pA8 + (size_t)m * 8);
      u = hp[0]; v4 = hp[1];
      h[1][0]=u.x; h[1][1]=u.y; h[1][2]=u.z; h[1][3]=u.w; h[1][4]=v4.x; h[1][5]=v4.y; h[1][6]=v4.z; h[1][7]=v4.w;
      hp = (const float4*)(pB8 + (size_t)m * 8);
      u = hp[0]; v4 = hp[1];
      h[2][0]=u.x; h[2][1]=u.y; h[2][2]=u.z; h[2][3]=u.w; h[2][4]=v4.x; h[2][5]=v4.y; h[2][6]=v4.z; h[2][7]=v4.w;
      h[3][0]=a0; h[3][1]=a1; h[3][2]=a2; h[3][3]=a3; h[3][4]=a4; h[3][5]=a5; h[3][6]=a6; h[3][7]=a7;
      float hv[8];
      #pragma unroll
      for (int j = 0; j < 8; ++j) {
        float v = b2[j];
        #pragma unroll
        for (int i2 = 0; i2 < 4; ++i2) {
          #pragma unroll
          for (int f = 0; f < 8; ++f) v += h[i2][f] * W2[i2 * 64 + f * 8 + j];
        }
        hv[j] = fmaxf(v, 0.0f);
      }
      float g0v = b3[0], sv1 = 0, sv2 = 0, sv3 = 0;
      #pragma unroll
      for (int f = 0; f < 8; ++f) {
        g0v += hv[f] * W3[f];
        sv1 += hv[f] * W3[8 + f];
        sv2 += hv[f] * W3[16 + f];
        sv3 += hv[f] * W3[24 + f];
      }
      g0[m] = g0v; s1o[m] = sv1; s2o[m] = sv2; s3o[m] = sv3;
    }
  }
  grid.sync();

  // ---- P7: uu = s2 + S s3 ----
  SPROP(s3o, uu[m] = s2o[m] + acc)
  grid.sync();

  // ---- P8: vv = s1 + S uu ----
  SPROP(uu, vv[m] = s1o[m] + acc)
  grid.sync();

  // ---- P9: h3 = relu(g0 + S vv) + layernorm stats ----
  double cs = 0.0, cs2 = 0.0;
  for (int m = nlo + g; m < nhi; m += 128) {
    int s0 = rowptr[m], s1e = rowptr[m + 1];
    float acc = 0.f;
    for (int i = s0 + r; i < s1e; i += 4) {
      int2 e = slice[i - ebase];
      acc += __int_as_float(e.y) * vv[e.x];
    }
    acc += __shfl_xor(acc, 1);
    acc += __shfl_xor(acc, 2);
    if (r == 0) {
      float hv3 = fmaxf(g0[m] + acc, 0.0f);
      h3[m] = hv3;
      cs += (double)hv3;
      cs2 += (double)hv3 * (double)hv3;
    }
  }
  #pragma unroll
  for (int o = 32; o > 0; o >>= 1) {
    cs  += __shfl_down(cs, o);
    cs2 += __shfl_down(cs2, o);
  }
  int lane = tid & 63, w = tid >> 6;
  if (lane == 0) { ls[w] = cs; ls2[w] = cs2; }
  __syncthreads();
  if (tid == 0) {
    double a = 0, b = 0;
    #pragma unroll
    for (int i = 0; i < 8; ++i) { a += ls[i]; b += ls2[i]; }
    atomicAdd(&stats[0], a);
    atomicAdd(&stats[1], b);
  }
}

// ---------------- layernorm key ----------------
__global__ void k_normkey(const float* __restrict__ h, const double* __restrict__ stats,
                          float* __restrict__ hn, unsigned* __restrict__ key) {
  int n = blockIdx.x * TPB + threadIdx.x;
  if (n >= NN) return;
  double mu = stats[0] / (double)NN;
  double var = stats[1] / (double)NN - mu * mu;
  if (var < 0.0) var = 0.0;
  double invs = 1.0 / sqrt(var + 1e-5);
  float v = (float)(((double)h[n] - mu) * invs);
  hn[n] = v;
  unsigned u = __float_as_uint(v);
  unsigned asc = (u & 0x80000000u) ? ~u : (u | 0x80000000u);
  key[n] = ~asc;
}

// ---------------- radix select (k-th largest) ----------------
template <int SHIFT, unsigned MASK>
__global__ void k_hist(const unsigned* __restrict__ key, const unsigned* __restrict__ prefix,
                       unsigned* __restrict__ hist) {
  __shared__ unsigned lh[256];
  lh[threadIdx.x] = 0;
  __syncthreads();
  int n = blockIdx.x * TPB + threadIdx.x;
  unsigned pfx = *prefix;
  if (n < NN) {
    unsigned kk = key[n];
    if ((kk & MASK) == pfx) atomicAdd(&lh[(kk >> SHIFT) & 0xffu], 1u);
  }
  __syncthreads();
  if (lh[threadIdx.x]) atomicAdd(&hist[threadIdx.x], lh[threadIdx.x]);
}

template <int SHIFT>
__global__ void k_pick(const unsigned* __restrict__ hist, unsigned* __restrict__ prefix,
                       int* __restrict__ target) {
  int t = *target;
  unsigned cum = 0;
  for (int b = 0; b < 256; ++b) {
    unsigned c = hist[b];
    if ((int)(cum + c) >= t) {
      *prefix |= ((unsigned)b) << SHIFT;
      *target = t - (int)cum;   // after last pass: rank within tied keys
      return;
    }
    cum += c;
  }
}

// ---------------- stable top-k membership ----------------
__global__ void k_count(const unsigned* __restrict__ key, const unsigned* __restrict__ prefix,
                        int* __restrict__ partials) {
  int n = blockIdx.x * TPB + threadIdx.x;
  unsigned T = *prefix;
  bool eq = (n < NN) && (key[n] == T);
  unsigned long long meq = __ballot(eq);
  __shared__ int ce[4];
  int lane = threadIdx.x & 63, w = threadIdx.x >> 6;
  if (lane == 0) ce[w] = __popcll(meq);
  __syncthreads();
  if (threadIdx.x == 0) partials[blockIdx.x] = ce[0] + ce[1] + ce[2] + ce[3];
}

__global__ void k_scan(const int* __restrict__ partials, int* __restrict__ offs) {
  if (threadIdx.x == 0) {
    int acc = 0;
    for (int b = 0; b < GRID_N; ++b) { offs[b] = acc; acc += partials[b]; }
  }
}

__global__ void k_final(const float* __restrict__ hn, const unsigned* __restrict__ key,
                        const unsigned* __restrict__ prefix, const int* __restrict__ offs,
                        const int* __restrict__ rptr, float* __restrict__ out) {
  int n = blockIdx.x * TPB + threadIdx.x;
  unsigned T = *prefix;
  int r = *rptr;
  bool eq = false, lt = false;
  float v = 0.0f;
  if (n < NN) {
    unsigned kk = key[n];
    eq = (kk == T);
    lt = (kk < T);
    v = hn[n];
  }
  unsigned long long m = __ballot(eq);
  __shared__ int wc[4];
  int lane = threadIdx.x & 63, w = threadIdx.x >> 6;
  if (lane == 0) wc[w] = __popcll(m);
  __syncthreads();
  int off = offs[blockIdx.x];
  for (int i = 0; i < w; ++i) off += wc[i];
  off += __popcll(m & ((1ull << lane) - 1ull));
  if (n >= NN) return;
  bool top = lt || (eq && off < r);
  unsigned asc = ~T;
  unsigned orig = (asc & 0x80000000u) ? (asc & 0x7fffffffu) : ~asc;
  float thr = fabsf(__uint_as_float(orig));
  float tkv = top ? 1.0f : -1.0f;
  float z = v - thr + tkv * 0.1f;
  out[2 * n]     = v;
  out[2 * n + 1] = 1.0f / (1.0f + expf(-z));
}

// ---------------- host launch ----------------
extern "C" void kernel_launch(void* const* d_in, const int* in_sizes, int n_in,
                              void* d_out, int out_size, void* d_ws, size_t ws_size,
                              hipStream_t stream) {
  const float* x       = (const float*)d_in[0];
  const float* ea      = (const float*)d_in[1];
  const float* W1      = (const float*)d_in[2];
  const float* b1      = (const float*)d_in[3];
  const float* W2      = (const float*)d_in[4];
  const float* b2      = (const float*)d_in[5];
  const float* W3      = (const float*)d_in[6];
  const float* b3      = (const float*)d_in[7];
  const int* ei        = (const int*)d_in[8];   // int32 on device
  const int* kptr      = (const int*)d_in[9];
  float* out           = (float*)d_out;

  const int* src = ei;        // row 0
  const int* dst = ei + NE;   // row 1

  char* ws = (char*)d_ws;
  size_t off = 0;
  auto alloc = [&](size_t bytes) -> void* {
    void* p = ws + off;
    off += (bytes + 255) & ~(size_t)255;
    return p;
  };

  int2*     ed       = (int2*)alloc((size_t)NE * 8);            // sorted CSR (src, |ea|)
  int2*     grouped  = (int2*)alloc((size_t)NE * 8);            // bucket-grouped edges
  int*      histT    = (int*)alloc((size_t)NBKT * NBLK * 4);
  int*      rowsum   = (int*)alloc((size_t)NBKT * 4);
  int*      bucketBase = (int*)alloc(((size_t)NBKT + 1) * 4);
  int*      rowptr   = (int*)alloc(((size_t)NN + 1) * 4);
  float2*   xd       = (float2*)alloc((size_t)NN * 8);          // packed (x, dinv)
  int*      nbp      = (int*)alloc(((size_t)NMB + 1) * 4);
  float*    pA       = (float*)alloc((size_t)NN * 4);
  float*    pB       = (float*)alloc((size_t)NN * 4);
  float*    uu       = (float*)alloc((size_t)NN * 4);
  float*    vv       = (float*)alloc((size_t)NN * 4);
  float*    pA8      = (float*)alloc((size_t)NN * 8 * 4);
  float*    pB8      = (float*)alloc((size_t)NN * 8 * 4);
  float*    h1       = (float*)alloc((size_t)NN * 8 * 4);
  float*    g0       = (float*)alloc((size_t)NN * 4);
  float*    s1       = (float*)alloc((size_t)NN * 4);
  float*    s2       = (float*)alloc((size_t)NN * 4);
  float*    s3       = (float*)alloc((size_t)NN * 4);
  float*    h3       = (float*)alloc((size_t)NN * 4);
  float*    hn       = (float*)alloc((size_t)NN * 4);
  unsigned* key      = (unsigned*)alloc((size_t)NN * 4);
  double*   stats    = (double*)alloc(2 * 8);
  unsigned* hist4    = (unsigned*)alloc(4 * 256 * 4);
  int*      partials = (int*)alloc(512 * 4);
  int*      offs     = (int*)alloc(512 * 4);
  unsigned* prefix   = (unsigned*)alloc(4);
  int*      target   = (int*)alloc(4);

  k_init<<<1, 1, 0, stream>>>(kptr, prefix, target, stats);

  // ---- build sorted CSR + xd + mega node ranges ----
  b_hist<<<NBLK, HTPB, 0, stream>>>(dst, histT);
  b_rowscan<<<NBKT, 64, 0, stream>>>(histT, rowsum);
  b_base<<<1, 64, 0, stream>>>(rowsum, bucketBase, rowptr);
  b_scatter<<<NBLK, HTPB, 0, stream>>>(src, dst, ea, histT, bucketBase, grouped);
  b_sortdeg<<<NBKT, 512, 0, stream>>>(bucketBase, grouped, x, ed, rowptr, xd);
  e_ranges<<<1, 1024, 0, stream>>>(rowptr, nbp);

  // ---- all 9 propagations in one cooperative kernel, LDS-resident edges ----
  {
    const int* rp = rowptr;
    const int2* edp = ed;
    const float2* xdp = xd;
    const int* nbq = nbp;
    void* margs[] = {
      (void*)&rp, (void*)&edp, (void*)&xdp, (void*)&nbq,
      (void*)&W1, (void*)&b1, (void*)&W2, (void*)&b2, (void*)&W3, (void*)&b3,
      (void*)&pA, (void*)&pB, (void*)&uu, (void*)&vv,
      (void*)&pA8, (void*)&pB8, (void*)&h1,
      (void*)&g0, (void*)&s1, (void*)&s2, (void*)&s3,
      (void*)&h3, (void*)&stats
    };
    hipLaunchCooperativeKernel((void*)mega, dim3(NMB), dim3(MTPB), margs, 0, stream);
  }

  // ---- layernorm key ----
  k_normkey<<<GRID_N, TPB, 0, stream>>>(h3, stats, hn, key);

  // ---- radix select: k-th largest ----
  hipMemsetAsync(hist4, 0, 4096, stream);
  k_hist<24, 0x00000000u><<<GRID_N, TPB, 0, stream>>>(key, prefix, hist4);
  k_pick<24><<<1, 1, 0, stream>>>(hist4, prefix, target);
  k_hist<16, 0xFF000000u><<<GRID_N, TPB, 0, stream>>>(key, prefix, hist4 + 256);
  k_pick<16><<<1, 1, 0, stream>>>(hist4 + 256, prefix, target);
  k_hist<8, 0xFFFF0000u><<<GRID_N, TPB, 0, stream>>>(key, prefix, hist4 + 512);
  k_pick<8><<<1, 1, 0, stream>>>(hist4 + 512, prefix, target);
  k_hist<0, 0xFFFFFF00u><<<GRID_N, TPB, 0, stream>>>(key, prefix, hist4 + 768);
  k_pick<0><<<1, 1, 0, stream>>>(hist4 + 768, prefix, target);

  // ---- stable membership + output ----
  k_count<<<GRID_N, TPB, 0, stream>>>(key, prefix, partials);
  k_scan<<<1, 64, 0, stream>>>(partials, offs);
  k_final<<<GRID_N, TPB, 0, stream>>>(hn, key, prefix, offs, target, out);
}